// Round 5
// baseline (153.703 us; speedup 1.0000x reference)
//
#include <hip/hip_runtime.h>
#include <stdint.h>
#include <stddef.h>

#define NG 128
#define SEQ 512
#define CIN 64
#define HID 128
#define NROWS (NG*SEQ)   // 65536
#define KLEN 256

typedef __attribute__((ext_vector_type(8))) short v8s;
typedef __attribute__((ext_vector_type(4))) short v4s;
typedef __attribute__((ext_vector_type(4))) float v4f;
typedef unsigned short u16;

__device__ __forceinline__ float b2f(u16 u) {
    union { unsigned int i; float f; } v; v.i = ((unsigned int)u) << 16; return v.f;
}
__device__ __forceinline__ u16 f2b(float f) {
    unsigned int x = __float_as_uint(f);
    unsigned int r = (x + 0x7fffu + ((x >> 16) & 1u)) >> 16;
    return (u16)r;
}

// ---------------- prep: f32 -> bf16 copies of weights only ----------------
__global__ void prep_kernel(const float* __restrict__ Wp, const float* __restrict__ Wi,
                            const float* __restrict__ Wo,
                            u16* __restrict__ Wpbf, u16* __restrict__ Wibf,
                            u16* __restrict__ Wobf) {
    int stride = gridDim.x * blockDim.x;
    int t0 = blockIdx.x * blockDim.x + threadIdx.x;
    for (int i = t0; i < 3 * 2 * HID * HID; i += stride) Wibf[i] = f2b(Wi[i]);
    for (int i = t0; i < 3 * HID * HID; i += stride) Wobf[i] = f2b(Wo[i]);
    for (int i = t0; i < HID * CIN; i += stride) Wpbf[i] = f2b(Wp[i]);
}

// ---------------- proj: h = x @ Wp^T + bp -> actT[g][c][l] (transposed) ----------------
__global__ __launch_bounds__(256, 4) void proj_kernel(const float* __restrict__ x,
                                                      const u16* __restrict__ Wp,
                                                      const float* __restrict__ bp,
                                                      u16* __restrict__ actT) {
    const int wave = threadIdx.x >> 6, lane = threadIdx.x & 63;
    const int fr = lane & 15, kgrp = lane >> 4, kb = kgrp * 8;
    const int m0 = blockIdx.x * 128 + wave * 32;
    const int g = blockIdx.x >> 2;
    const int lloc0 = (blockIdx.x & 3) * 128 + wave * 32;

    v4f acc[2][8];
#pragma unroll
    for (int rt = 0; rt < 2; ++rt)
#pragma unroll
        for (int nt = 0; nt < 8; ++nt) acc[rt][nt] = (v4f){0.f, 0.f, 0.f, 0.f};

#pragma unroll
    for (int ks = 0; ks < 2; ++ks) {
        v8s a[2];
#pragma unroll
        for (int rt = 0; rt < 2; ++rt) {
            const float* ap = x + (size_t)(m0 + rt * 16 + fr) * CIN + ks * 32 + kb;
            float4 f0 = *(const float4*)ap;
            float4 f1 = *(const float4*)(ap + 4);
            v8s t;
            t[0] = (short)f2b(f0.x); t[1] = (short)f2b(f0.y);
            t[2] = (short)f2b(f0.z); t[3] = (short)f2b(f0.w);
            t[4] = (short)f2b(f1.x); t[5] = (short)f2b(f1.y);
            t[6] = (short)f2b(f1.z); t[7] = (short)f2b(f1.w);
            a[rt] = t;
        }
#pragma unroll
        for (int nt = 0; nt < 8; ++nt) {
            v8s b = *(const v8s*)(Wp + (size_t)(nt * 16 + fr) * CIN + ks * 32 + kb);
            acc[0][nt] = __builtin_amdgcn_mfma_f32_16x16x32_bf16(a[0], b, acc[0][nt], 0, 0, 0);
            acc[1][nt] = __builtin_amdgcn_mfma_f32_16x16x32_bf16(a[1], b, acc[1][nt], 0, 0, 0);
        }
    }
#pragma unroll
    for (int rt = 0; rt < 2; ++rt)
#pragma unroll
        for (int nt = 0; nt < 8; ++nt) {
            int col = nt * 16 + fr;
            float bb = bp[col];
            v4s pk;
#pragma unroll
            for (int r = 0; r < 4; ++r) pk[r] = (short)f2b(acc[rt][nt][r] + bb);
            *(v4s*)(actT + ((size_t)g * HID + col) * SEQ + lloc0 + rt * 16 + kgrp * 4) = pk;
        }
}

// ---------------- chunkh: 16-row chunk decayed sums H[g][s][c], s in [0,32) ----------------
__global__ __launch_bounds__(512) void chunkh_kernel(const u16* __restrict__ actT,
                                                     float* __restrict__ H,
                                                     const float* __restrict__ log_tau, int d) {
    const int g = blockIdx.x >> 3, qt = blockIdx.x & 7;
    const int c = threadIdx.x & 127, sc = threadIdx.x >> 7;   // sc 0..3
    const int s = qt * 4 + sc;                                 // 0..31
    const int l0 = s * 16;
    float tau = fmaxf(expf(log_tau[d * HID + c]), 0.001f);
    float q = expf(-1.0f / tau);
    float lq = -(1.0f / tau) * 1.44269504089f;
    const u16* xc = actT + ((size_t)g * HID + c) * SEQ + l0;
    v8s x0 = *(const v8s*)(xc);
    v8s x1 = *(const v8s*)(xc + 8);
    float sp = exp2f((float)l0 * lq);
    float acc = 0.f;
#pragma unroll
    for (int j = 0; j < 8; ++j) { acc += sp * b2f((u16)x0[j]); sp *= q; }
#pragma unroll
    for (int j = 0; j < 8; ++j) { acc += sp * b2f((u16)x1[j]); sp *= q; }
    H[(size_t)g * 4096 + s * 128 + c] = acc;
}

// ---------------- fused: scan -> GEMM1/GLU -> GEMM2 -> LN -> actT (64-row tiles) ----------------
__global__ __launch_bounds__(512, 4) void fused_kernel(const u16* __restrict__ actT,
                                                       const float* __restrict__ H,
                                                       const u16* __restrict__ Win,
                                                       const u16* __restrict__ Wout,
                                                       const float* __restrict__ b_in,
                                                       const float* __restrict__ b_out,
                                                       const float* __restrict__ gamma,
                                                       const float* __restrict__ beta,
                                                       const float* __restrict__ log_tau, int d,
                                                       u16* __restrict__ actTout) {
    __shared__ u16 ylds[64 * 128];    // 16 KB, XOR-swizzled
    __shared__ u16 ulds[64 * 128];    // 16 KB, XOR-swizzled
    __shared__ float2 red[8][64];     // 4 KB LN partials
    __shared__ float2 murstd[64];     // 512 B
    const int tid = threadIdx.x;
    const int g = blockIdx.x >> 3, tile = blockIdx.x & 7;
    const int r0 = tile * 64;

    // ---- scan phase: thread (c, sc) produces y rows [r0+sc*16, +16) for channel c ----
    {
        const int c = tid & 127, sc = tid >> 7;
        const int l0 = r0 + sc * 16;
        const u16* xc = actT + ((size_t)g * HID + c) * SEQ;
        const bool hasd = (r0 >= KLEN);           // block-uniform (KLEN = 4 tiles)
        // issue x loads early
        v8s xv0 = *(const v8s*)(xc + l0);
        v8s xv1 = *(const v8s*)(xc + l0 + 8);
        v8s xd0 = {}, xd1 = {};
        if (hasd) {
            xd0 = *(const v8s*)(xc + l0 - KLEN);
            xd1 = *(const v8s*)(xc + l0 - KLEN + 8);
        }
        float tau = fmaxf(expf(log_tau[d * HID + c]), 0.001f);
        float q = expf(-1.0f / tau);
        float lq = -(1.0f / tau) * 1.44269504089f;
        float S = (q < 0.9999999f) ? (1.0f - exp2f(256.0f * lq)) / (1.0f - q) : 256.0f;
        float invS = 1.0f / (S + 1e-8f);
        float qinv = exp2f(-lq);
        // carry-in prefixes from 16-row chunk sums
        const float* Hg = H + (size_t)g * 4096;
        const int s0 = l0 >> 4;
        float Pin = 0.f, Pdin = 0.f;
#pragma unroll
        for (int s = 0; s < 32; ++s) {
            float hv = Hg[s * 128 + c];
            if (s < s0) Pin += hv;
            if (s < s0 - 16) Pdin += hv;
        }
        float P = Pin, Pd = Pdin;
        float sp = exp2f((float)l0 * lq);
        float w = exp2f((float)(255 - l0) * lq) * invS;
        float spd = hasd ? exp2f((float)(l0 - KLEN) * lq) : 0.f;
        char* ybase = (char*)ylds + (sc * 16) * 256;
#pragma unroll
        for (int j = 0; j < 8; ++j) {
            P += sp * b2f((u16)xv0[j]);
            float Pold = 0.f;
            if (hasd) { Pd += spd * b2f((u16)xd0[j]); Pold = Pd; spd *= q; }
            *(u16*)(ybase + j * 256 + ((2 * c) ^ ((j & 7) << 4))) = f2b(w * (P - Pold));
            sp *= q; w *= qinv;
        }
#pragma unroll
        for (int j = 0; j < 8; ++j) {
            P += sp * b2f((u16)xv1[j]);
            float Pold = 0.f;
            if (hasd) { Pd += spd * b2f((u16)xd1[j]); Pold = Pd; spd *= q; }
            const int lt = 8 + j;
            *(u16*)(ybase + lt * 256 + ((2 * c) ^ ((lt & 7) << 4))) = f2b(w * (P - Pold));
            sp *= q; w *= qinv;
        }
    }

    const int wave = tid >> 6, lane = tid & 63;
    const int fr = lane & 15, kgrp = lane >> 4, kb = kgrp * 8;

    // weight-stationary fragments (loaded while scan finishes in other waves)
    v8s b1a[4], b1g[4], b2[4];
#pragma unroll
    for (int ks = 0; ks < 4; ++ks) {
        b1a[ks] = *(const v8s*)(Win + (size_t)(wave * 16 + fr) * HID + ks * 32 + kb);
        b1g[ks] = *(const v8s*)(Win + (size_t)((wave + 8) * 16 + fr) * HID + ks * 32 + kb);
        b2[ks]  = *(const v8s*)(Wout + (size_t)(wave * 16 + fr) * HID + ks * 32 + kb);
    }
    const float ba = b_in[wave * 16 + fr];
    const float bg = b_in[HID + wave * 16 + fr];
    const float bo = b_out[wave * 16 + fr];

    __syncthreads();   // S1: ylds ready

    // GEMM1 (n-split pairs, B in regs) + in-register GLU -> swizzled ulds
#pragma unroll
    for (int rt = 0; rt < 4; ++rt) {
        const int arow = rt * 16 + fr;
        const char* abase = (const char*)ylds + arow * 256;
        const int asw = (arow & 7) << 4;
        v8s af[4];
#pragma unroll
        for (int ks = 0; ks < 4; ++ks)
            af[ks] = *(const v8s*)(abase + ((ks * 64 + kgrp * 16) ^ asw));
        v4f a0 = (v4f){0.f, 0.f, 0.f, 0.f}, a1 = (v4f){0.f, 0.f, 0.f, 0.f};
#pragma unroll
        for (int ks = 0; ks < 4; ++ks) {
            a0 = __builtin_amdgcn_mfma_f32_16x16x32_bf16(af[ks], b1a[ks], a0, 0, 0, 0);
            a1 = __builtin_amdgcn_mfma_f32_16x16x32_bf16(af[ks], b1g[ks], a1, 0, 0, 0);
        }
        const int colb = (wave * 16 + fr) * 2;
#pragma unroll
        for (int r = 0; r < 4; ++r) {
            const int urow = rt * 16 + kgrp * 4 + r;
            float av = a0[r] + ba;
            float gv = a1[r] + bg;
            float u = av * (1.0f / (1.0f + __expf(-gv)));
            *(u16*)((char*)ulds + urow * 256 + (colb ^ ((urow & 7) << 4))) = f2b(u);
        }
    }
    __syncthreads();   // S2: ulds ready

    // GEMM2 col-split: wave computes cols [wave*16,+16) for all 64 rows, B in regs
    v4f acc2[4];
#pragma unroll
    for (int rt = 0; rt < 4; ++rt) acc2[rt] = (v4f){0.f, 0.f, 0.f, 0.f};
#pragma unroll
    for (int rt = 0; rt < 4; ++rt) {
        const int arow = rt * 16 + fr;
        const char* abase = (const char*)ulds + arow * 256;
        const int asw = (arow & 7) << 4;
#pragma unroll
        for (int ks = 0; ks < 4; ++ks) {
            v8s af = *(const v8s*)(abase + ((ks * 64 + kgrp * 16) ^ asw));
            acc2[rt] = __builtin_amdgcn_mfma_f32_16x16x32_bf16(af, b2[ks], acc2[rt], 0, 0, 0);
        }
    }

    // z = y2 + b_out + y; 16-lane shfl partials -> red[wave][row]
    const int colb = (wave * 16 + fr) * 2;
    float zar[4][4];
#pragma unroll
    for (int rt = 0; rt < 4; ++rt) {
#pragma unroll
        for (int r = 0; r < 4; ++r) {
            const int row = rt * 16 + kgrp * 4 + r;
            float yv = b2f(*(const u16*)((const char*)ylds + row * 256 + (colb ^ ((row & 7) << 4))));
            float zz = acc2[rt][r] + bo + yv;
            zar[rt][r] = zz;
            float a = zz, b = zz * zz;
            a += __shfl_xor(a, 1); b += __shfl_xor(b, 1);
            a += __shfl_xor(a, 2); b += __shfl_xor(b, 2);
            a += __shfl_xor(a, 4); b += __shfl_xor(b, 4);
            a += __shfl_xor(a, 8); b += __shfl_xor(b, 8);
            if (fr == rt * 4 + r) red[wave][row] = make_float2(a, b);
        }
    }
    __syncthreads();   // S3: red ready

    if (tid < 64) {
        float a = 0.f, b = 0.f;
#pragma unroll
        for (int j = 0; j < 8; ++j) { float2 v = red[j][tid]; a += v.x; b += v.y; }
        float mu = a * (1.0f / 128.0f);
        float var = b * (1.0f / 128.0f) - mu * mu;
        murstd[tid] = make_float2(mu, rsqrtf(var + 1e-5f));
    }
    __syncthreads();   // S4: murstd ready

    // epilogue: normalize + transposed packed store
    const int col = wave * 16 + fr;
    const float gmv = gamma[col], btv = beta[col];
#pragma unroll
    for (int rt = 0; rt < 4; ++rt) {
        v4s pk;
#pragma unroll
        for (int r = 0; r < 4; ++r) {
            float2 ms = murstd[rt * 16 + kgrp * 4 + r];
            pk[r] = (short)f2b((zar[rt][r] - ms.x) * ms.y * gmv + btv);
        }
        *(v4s*)(actTout + ((size_t)g * HID + col) * SEQ + r0 + rt * 16 + kgrp * 4) = pk;
    }
}

// ---------------- final mean over L (contiguous actT reads) ----------------
__global__ __launch_bounds__(512) void mean_kernel(const u16* __restrict__ actT, float* __restrict__ out) {
    __shared__ float red[4][128];
    const int g = blockIdx.x;
    const int c = threadIdx.x & 127, q4 = threadIdx.x >> 7;
    const u16* xc = actT + ((size_t)g * HID + c) * SEQ + q4 * 128;
    float s = 0.f;
#pragma unroll
    for (int v = 0; v < 16; ++v) {
        v8s x = *(const v8s*)(xc + v * 8);
#pragma unroll
        for (int j = 0; j < 8; ++j) s += b2f((u16)x[j]);
    }
    red[q4][c] = s;
    __syncthreads();
    if (threadIdx.x < 128) {
        float tot = red[0][c] + red[1][c] + red[2][c] + red[3][c];
        out[g * HID + c] = tot * (1.0f / 512.0f);
    }
}

extern "C" void kernel_launch(void* const* d_in, const int* in_sizes, int n_in,
                              void* d_out, int out_size, void* d_ws, size_t ws_size,
                              hipStream_t stream) {
    const float* x       = (const float*)d_in[0];
    const float* Wp      = (const float*)d_in[2];
    const float* bp      = (const float*)d_in[3];
    const float* log_tau = (const float*)d_in[4];
    const float* Wi      = (const float*)d_in[5];
    const float* bi      = (const float*)d_in[6];
    const float* Wo      = (const float*)d_in[7];
    const float* bo      = (const float*)d_in[8];
    const float* gm      = (const float*)d_in[9];
    const float* bt      = (const float*)d_in[10];
    float* out = (float*)d_out;

    char* ws = (char*)d_ws;
    const size_t ACT_BYTES = (size_t)NROWS * HID * 2;       // 16 MB
    u16* actA  = (u16*)(ws);
    u16* actB  = (u16*)(ws + ACT_BYTES);
    float* Hbuf = (float*)(ws + 2 * ACT_BYTES);              // 2 MB
    char* wbase = ws + 2 * ACT_BYTES + (size_t)NG * 4096 * 4;
    u16* Wibf = (u16*)(wbase);
    u16* Wobf = (u16*)(wbase + (size_t)3 * 2 * HID * HID * 2);
    u16* Wpbf = (u16*)(wbase + (size_t)3 * 2 * HID * HID * 2 + (size_t)3 * HID * HID * 2);

    prep_kernel<<<128, 256, 0, stream>>>(Wp, Wi, Wo, Wpbf, Wibf, Wobf);
    proj_kernel<<<NROWS / 128, 256, 0, stream>>>(x, Wpbf, bp, actA);

    u16* cur = actA, *nxt = actB;
    for (int d = 0; d < 3; ++d) {
        chunkh_kernel<<<NG * 8, 512, 0, stream>>>(cur, Hbuf, log_tau, d);
        fused_kernel<<<NG * 8, 512, 0, stream>>>(cur, Hbuf,
            Wibf + (size_t)d * 2 * HID * HID, Wobf + (size_t)d * HID * HID,
            bi + d * 2 * HID, bo + d * HID, gm + d * HID, bt + d * HID,
            log_tau, d, nxt);
        u16* t = cur; cur = nxt; nxt = t;
    }
    mean_kernel<<<NG, 512, 0, stream>>>(cur, out);
}

// Round 6
// 135.134 us; speedup vs baseline: 1.1374x; 1.1374x over previous
//
#include <hip/hip_runtime.h>
#include <stdint.h>
#include <stddef.h>

#define NG 128
#define SEQ 512
#define CIN 64
#define HID 128
#define NROWS (NG*SEQ)   // 65536
#define KLEN 256
#define YS 272           // ylds/ulds row stride (bytes): 256 data + 16 pad (bank skew)

typedef __attribute__((ext_vector_type(8))) short v8s;
typedef __attribute__((ext_vector_type(4))) short v4s;
typedef __attribute__((ext_vector_type(4))) float v4f;
typedef __attribute__((ext_vector_type(2))) unsigned v2u;
typedef unsigned short u16;

__device__ __forceinline__ float b2f(u16 u) {
    union { unsigned int i; float f; } v; v.i = ((unsigned int)u) << 16; return v.f;
}
__device__ __forceinline__ u16 f2b(float f) {
    unsigned int x = __float_as_uint(f);
    unsigned int r = (x + 0x7fffu + ((x >> 16) & 1u)) >> 16;
    return (u16)r;
}
// packed f32x2 -> bf16x2 (RNE), single HW inst
__device__ __forceinline__ unsigned cvtpk(float lo, float hi) {
    unsigned r;
    asm("v_cvt_pk_bf16_f32 %0, %1, %2" : "=v"(r) : "v"(lo), "v"(hi));
    return r;
}
__device__ __forceinline__ float sigf(float x) { return 1.0f / (1.0f + __expf(-x)); }

// ---------------- prep: f32 -> bf16 weights ----------------
__global__ void prep_kernel(const float* __restrict__ Wp, const float* __restrict__ Wi,
                            const float* __restrict__ Wo,
                            u16* __restrict__ Wpbf, u16* __restrict__ Wibf,
                            u16* __restrict__ Wobf) {
    int stride = gridDim.x * blockDim.x;
    int t0 = blockIdx.x * blockDim.x + threadIdx.x;
    for (int i = t0; i < 3 * 2 * HID * HID; i += stride) Wibf[i] = f2b(Wi[i]);
    for (int i = t0; i < 3 * HID * HID; i += stride) Wobf[i] = f2b(Wo[i]);
    for (int i = t0; i < HID * CIN; i += stride) Wpbf[i] = f2b(Wp[i]);
}

// ---------------- proj: h = x @ Wp^T + bp -> actR[g*512+l][c] (row-major) ----------------
// swapped operands: mfma(A=Wp rows, B=x rows) -> D[c][l]: lane fr=l, 4 consecutive c
__global__ __launch_bounds__(256, 4) void proj_kernel(const float* __restrict__ x,
                                                      const u16* __restrict__ Wp,
                                                      const float* __restrict__ bp,
                                                      u16* __restrict__ actR) {
    const int wave = threadIdx.x >> 6, lane = threadIdx.x & 63;
    const int fr = lane & 15, kgrp = lane >> 4;
    const int l = blockIdx.x * 64 + wave * 16 + fr;   // this lane's output row
    const int n0 = kgrp * 4;                           // channel quad base (per nt add nt*16)

    v4f acc[8];
#pragma unroll
    for (int nt = 0; nt < 8; ++nt) acc[nt] = (v4f){0.f, 0.f, 0.f, 0.f};

#pragma unroll
    for (int ks = 0; ks < 2; ++ks) {
        // B-frag: x row l, k-window ks*32 + kgrp*8
        const float* ap = x + (size_t)l * CIN + ks * 32 + kgrp * 8;
        float4 f0 = *(const float4*)ap;
        float4 f1 = *(const float4*)(ap + 4);
        union { unsigned u[4]; v8s s; } bf;
        bf.u[0] = cvtpk(f0.x, f0.y); bf.u[1] = cvtpk(f0.z, f0.w);
        bf.u[2] = cvtpk(f1.x, f1.y); bf.u[3] = cvtpk(f1.z, f1.w);
#pragma unroll
        for (int nt = 0; nt < 8; ++nt) {
            v8s a = *(const v8s*)(Wp + (size_t)(nt * 16 + fr) * CIN + ks * 32 + kgrp * 8);
            acc[nt] = __builtin_amdgcn_mfma_f32_16x16x32_bf16(a, bf.s, acc[nt], 0, 0, 0);
        }
    }
#pragma unroll
    for (int nt = 0; nt < 8; ++nt) {
        const int c = nt * 16 + n0;
        float4 bb = *(const float4*)(bp + c);
        union { unsigned u[2]; v4s s; } pk;
        pk.u[0] = cvtpk(acc[nt][0] + bb.x, acc[nt][1] + bb.y);
        pk.u[1] = cvtpk(acc[nt][2] + bb.z, acc[nt][3] + bb.w);
        *(v4s*)(actR + (size_t)l * HID + c) = pk.s;
    }
}

// ---------------- chunkh: exclusive-prefix carries Pre[g][64][128] ----------------
// 8-row chunks; Pre[s][c] = sum_{s'<s} H[s'][c], H = decayed chunk sums (global exponent q^l)
__global__ __launch_bounds__(512) void chunkh_kernel(const u16* __restrict__ actR,
                                                     float* __restrict__ Pre,
                                                     const float* __restrict__ log_tau, int d) {
    __shared__ float2 t8[8][64];
    const int tid = threadIdx.x;
    const int g = blockIdx.x;
    const int cp = tid & 63, sc = tid >> 6;
    const int c0 = 2 * cp;
    const unsigned* x32 = (const unsigned*)(actR + (size_t)g * (SEQ * HID));
    float q0, q1, sp0, sp1;
    {
        float tau0 = fmaxf(expf(log_tau[d * HID + c0]), 0.001f);
        float tau1 = fmaxf(expf(log_tau[d * HID + c0 + 1]), 0.001f);
        float lq0 = -(1.0f / tau0) * 1.44269504089f;
        float lq1 = -(1.0f / tau1) * 1.44269504089f;
        q0 = exp2f(lq0); q1 = exp2f(lq1);
        sp0 = exp2f((float)(sc * 64) * lq0);
        sp1 = exp2f((float)(sc * 64) * lq1);
    }
    float h0[8], h1[8];
#pragma unroll
    for (int s = 0; s < 8; ++s) {
        float a0 = 0.f, a1 = 0.f;
#pragma unroll
        for (int j = 0; j < 8; ++j) {
            unsigned xv = x32[(size_t)(sc * 64 + s * 8 + j) * 64 + cp];
            a0 += sp0 * b2f((u16)(xv & 0xffff));
            a1 += sp1 * b2f((u16)(xv >> 16));
            sp0 *= q0; sp1 *= q1;
        }
        h0[s] = a0; h1[s] = a1;
    }
    float T0 = 0.f, T1 = 0.f;
#pragma unroll
    for (int s = 0; s < 8; ++s) { T0 += h0[s]; T1 += h1[s]; }
    t8[sc][cp] = make_float2(T0, T1);
    __syncthreads();
    float b0 = 0.f, b1 = 0.f;
    for (int s = 0; s < sc; ++s) { float2 v = t8[s][cp]; b0 += v.x; b1 += v.y; }
    float* PreG = Pre + (size_t)g * 64 * HID;
#pragma unroll
    for (int s = 0; s < 8; ++s) {
        *(float2*)(PreG + (size_t)(sc * 8 + s) * HID + c0) = make_float2(b0, b1);
        b0 += h0[s]; b1 += h1[s];
    }
}

// ---------------- fused: scan -> GEMM1/GLU -> GEMM2 -> LN -> actR ----------------
__global__ __launch_bounds__(512, 4) void fused_kernel(const u16* __restrict__ actR,
                                                       const float* __restrict__ Pre,
                                                       const u16* __restrict__ Win,
                                                       const u16* __restrict__ Wout,
                                                       const float* __restrict__ b_in,
                                                       const float* __restrict__ b_out,
                                                       const float* __restrict__ gamma,
                                                       const float* __restrict__ beta,
                                                       const float* __restrict__ log_tau, int d,
                                                       u16* __restrict__ actRout) {
    __shared__ __align__(16) char ylds[64 * YS];   // y, [l][c] bf16, XOR-swizzled, padded stride
    __shared__ __align__(16) char ulds[64 * YS];   // u, same layout
    __shared__ float2 red[8][64];
    __shared__ float2 murstd[64];
    const int tid = threadIdx.x;
    const int g = blockIdx.x >> 3, tile = blockIdx.x & 7;
    const int r0 = tile * 64;
    const size_t gbase = (size_t)g * (SEQ * HID);

    // ---- scan: thread (cp, sc) -> channels {2cp,2cp+1}, rows [r0+sc*8, +8) ----
    {
        const int cp = tid & 63, sc = tid >> 6;
        const int c0 = 2 * cp;
        const int l0 = r0 + sc * 8;
        const bool hasd = (r0 >= KLEN);            // block-uniform
        const unsigned* x32 = (const unsigned*)(actR + gbase);
        unsigned xw[8], xdw[8];
#pragma unroll
        for (int j = 0; j < 8; ++j) xw[j] = x32[(size_t)(l0 + j) * 64 + cp];
        if (hasd) {
#pragma unroll
            for (int j = 0; j < 8; ++j) xdw[j] = x32[(size_t)(l0 - KLEN + j) * 64 + cp];
        }
        const float* PreG = Pre + ((size_t)g * 64 + (l0 >> 3)) * HID + c0;
        float2 pin = *(const float2*)PreG;
        float2 pdin = hasd ? *(const float2*)(PreG - 32 * HID) : make_float2(0.f, 0.f);
        float P[2], Pd[2], sp[2], w[2], spd[2], q[2], qinv[2];
#pragma unroll
        for (int k = 0; k < 2; ++k) {
            float tau = fmaxf(expf(log_tau[d * HID + c0 + k]), 0.001f);
            float lq = -(1.0f / tau) * 1.44269504089f;
            q[k] = exp2f(lq);
            float S = (q[k] < 0.9999999f) ? (1.0f - exp2f(256.0f * lq)) / (1.0f - q[k]) : 256.0f;
            float invS = 1.0f / (S + 1e-8f);
            qinv[k] = exp2f(-lq);
            sp[k] = exp2f((float)l0 * lq);
            w[k] = exp2f((float)(255 - l0) * lq) * invS;
            spd[k] = hasd ? exp2f((float)(l0 - KLEN) * lq) : 0.f;
            P[k] = k ? pin.y : pin.x;
            Pd[k] = k ? pdin.y : pdin.x;
        }
#pragma unroll
        for (int j = 0; j < 8; ++j) {
            const int lt = sc * 8 + j;
            float y0, y1;
            {
                P[0] += sp[0] * b2f((u16)(xw[j] & 0xffff)); sp[0] *= q[0];
                P[1] += sp[1] * b2f((u16)(xw[j] >> 16));    sp[1] *= q[1];
                float Po0 = 0.f, Po1 = 0.f;
                if (hasd) {
                    Pd[0] += spd[0] * b2f((u16)(xdw[j] & 0xffff)); spd[0] *= q[0]; Po0 = Pd[0];
                    Pd[1] += spd[1] * b2f((u16)(xdw[j] >> 16));    spd[1] *= q[1]; Po1 = Pd[1];
                }
                y0 = w[0] * (P[0] - Po0); w[0] *= qinv[0];
                y1 = w[1] * (P[1] - Po1); w[1] *= qinv[1];
            }
            *(unsigned*)(ylds + lt * YS + ((4 * cp) ^ ((lt & 7) << 4))) = cvtpk(y0, y1);
        }
    }

    const int wave = tid >> 6, lane = tid & 63;
    const int fr = lane & 15, kgrp = lane >> 4;
    const int n0 = wave * 16 + kgrp * 4;     // this lane's channel quad (GEMM out dim)

    // weight-stationary fragments (A-operands): Win a-rows, g-rows, Wout rows
    v8s b1a[4], b1g[4], b2[4];
#pragma unroll
    for (int ks = 0; ks < 4; ++ks) {
        b1a[ks] = *(const v8s*)(Win + (size_t)(wave * 16 + fr) * HID + ks * 32 + kgrp * 8);
        b1g[ks] = *(const v8s*)(Win + (size_t)((wave + 8) * 16 + fr) * HID + ks * 32 + kgrp * 8);
        b2[ks]  = *(const v8s*)(Wout + (size_t)(wave * 16 + fr) * HID + ks * 32 + kgrp * 8);
    }
    const float4 ba4 = *(const float4*)(b_in + n0);
    const float4 bg4 = *(const float4*)(b_in + HID + n0);
    const float4 bo4 = *(const float4*)(b_out + n0);

    __syncthreads();   // S1: ylds ready

    // ---- GEMM1 swapped (D[n][l]) + in-reg GLU -> ulds b64 packed ----
#pragma unroll
    for (int rt = 0; rt < 4; ++rt) {
        const int arow = rt * 16 + fr;
        const char* abase = ylds + arow * YS;
        const int asw = (arow & 7) << 4;
        v8s af[4];
#pragma unroll
        for (int ks = 0; ks < 4; ++ks)
            af[ks] = *(const v8s*)(abase + ((ks * 64 + kgrp * 16) ^ asw));
        v4f a0 = (v4f){0.f, 0.f, 0.f, 0.f}, a1 = (v4f){0.f, 0.f, 0.f, 0.f};
#pragma unroll
        for (int ks = 0; ks < 4; ++ks) {
            a0 = __builtin_amdgcn_mfma_f32_16x16x32_bf16(b1a[ks], af[ks], a0, 0, 0, 0);
            a1 = __builtin_amdgcn_mfma_f32_16x16x32_bf16(b1g[ks], af[ks], a1, 0, 0, 0);
        }
        float u0 = (a0[0] + ba4.x) * sigf(a1[0] + bg4.x);
        float u1 = (a0[1] + ba4.y) * sigf(a1[1] + bg4.y);
        float u2 = (a0[2] + ba4.z) * sigf(a1[2] + bg4.z);
        float u3 = (a0[3] + ba4.w) * sigf(a1[3] + bg4.w);
        v2u pk;
        pk[0] = cvtpk(u0, u1); pk[1] = cvtpk(u2, u3);
        *(v2u*)(ulds + arow * YS + ((2 * n0) ^ asw)) = pk;
    }
    __syncthreads();   // S2: ulds ready

    // ---- GEMM2 swapped: acc2[rt][r] = z at (n = n0+r, l = rt*16+fr) ----
    v4f acc2[4];
#pragma unroll
    for (int rt = 0; rt < 4; ++rt) acc2[rt] = (v4f){0.f, 0.f, 0.f, 0.f};
#pragma unroll
    for (int rt = 0; rt < 4; ++rt) {
        const int arow = rt * 16 + fr;
        const char* abase = ulds + arow * YS;
        const int asw = (arow & 7) << 4;
#pragma unroll
        for (int ks = 0; ks < 4; ++ks) {
            v8s af = *(const v8s*)(abase + ((ks * 64 + kgrp * 16) ^ asw));
            acc2[rt] = __builtin_amdgcn_mfma_f32_16x16x32_bf16(b2[ks], af, acc2[rt], 0, 0, 0);
        }
    }
    // residual + LN partials (per-lane values are row-aligned now)
#pragma unroll
    for (int rt = 0; rt < 4; ++rt) {
        const int l = rt * 16 + fr;
        v4s yv = *(const v4s*)(ylds + l * YS + ((2 * n0) ^ ((l & 7) << 4)));
        float z0 = acc2[rt][0] + bo4.x + b2f((u16)yv[0]);
        float z1 = acc2[rt][1] + bo4.y + b2f((u16)yv[1]);
        float z2 = acc2[rt][2] + bo4.z + b2f((u16)yv[2]);
        float z3 = acc2[rt][3] + bo4.w + b2f((u16)yv[3]);
        acc2[rt][0] = z0; acc2[rt][1] = z1; acc2[rt][2] = z2; acc2[rt][3] = z3;
        float s = z0 + z1 + z2 + z3;
        float sq = z0 * z0 + z1 * z1 + z2 * z2 + z3 * z3;
        s += __shfl_xor(s, 16); sq += __shfl_xor(sq, 16);
        s += __shfl_xor(s, 32); sq += __shfl_xor(sq, 32);
        if (lane < 16) red[wave][l] = make_float2(s, sq);
    }
    __syncthreads();   // S3: red ready

    if (tid < 64) {
        float a = 0.f, b = 0.f;
#pragma unroll
        for (int j = 0; j < 8; ++j) { float2 v = red[j][tid]; a += v.x; b += v.y; }
        float mu = a * (1.0f / 128.0f);
        float var = b * (1.0f / 128.0f) - mu * mu;
        murstd[tid] = make_float2(mu, rsqrtf(var + 1e-5f));
    }
    __syncthreads();   // S4: murstd ready

    // epilogue: normalize + packed coalesced b64 store to actRout[l][c]
    const float4 gm4 = *(const float4*)(gamma + n0);
    const float4 bt4 = *(const float4*)(beta + n0);
#pragma unroll
    for (int rt = 0; rt < 4; ++rt) {
        const int l = rt * 16 + fr;
        float2 ms = murstd[l];
        float o0 = (acc2[rt][0] - ms.x) * ms.y * gm4.x + bt4.x;
        float o1 = (acc2[rt][1] - ms.x) * ms.y * gm4.y + bt4.y;
        float o2 = (acc2[rt][2] - ms.x) * ms.y * gm4.z + bt4.z;
        float o3 = (acc2[rt][3] - ms.x) * ms.y * gm4.w + bt4.w;
        union { unsigned u[2]; v4s s; } pk;
        pk.u[0] = cvtpk(o0, o1); pk.u[1] = cvtpk(o2, o3);
        *(v4s*)(actRout + gbase + (size_t)(r0 + l) * HID + n0) = pk.s;
    }
}

// ---------------- final mean over L (coalesced [l][c] reads) ----------------
__global__ __launch_bounds__(512) void mean_kernel(const u16* __restrict__ actR, float* __restrict__ out) {
    __shared__ float2 red[8][64];
    const int tid = threadIdx.x;
    const int g = blockIdx.x;
    const int cp = tid & 63, lq8 = tid >> 6;
    const unsigned* x32 = (const unsigned*)(actR + (size_t)g * (SEQ * HID));
    float s0 = 0.f, s1 = 0.f;
#pragma unroll
    for (int j = 0; j < 64; ++j) {
        unsigned v = x32[(size_t)(lq8 * 64 + j) * 64 + cp];
        s0 += b2f((u16)(v & 0xffff));
        s1 += b2f((u16)(v >> 16));
    }
    red[lq8][cp] = make_float2(s0, s1);
    __syncthreads();
    if (tid < 64) {
        float a = 0.f, b = 0.f;
#pragma unroll
        for (int j = 0; j < 8; ++j) { float2 v = red[j][tid]; a += v.x; b += v.y; }
        *(float2*)(out + (size_t)g * HID + 2 * tid) =
            make_float2(a * (1.0f / 512.0f), b * (1.0f / 512.0f));
    }
}

extern "C" void kernel_launch(void* const* d_in, const int* in_sizes, int n_in,
                              void* d_out, int out_size, void* d_ws, size_t ws_size,
                              hipStream_t stream) {
    const float* x       = (const float*)d_in[0];
    const float* Wp      = (const float*)d_in[2];
    const float* bp      = (const float*)d_in[3];
    const float* log_tau = (const float*)d_in[4];
    const float* Wi      = (const float*)d_in[5];
    const float* bi      = (const float*)d_in[6];
    const float* Wo      = (const float*)d_in[7];
    const float* bo      = (const float*)d_in[8];
    const float* gm      = (const float*)d_in[9];
    const float* bt      = (const float*)d_in[10];
    float* out = (float*)d_out;

    char* ws = (char*)d_ws;
    const size_t ACT_BYTES = (size_t)NROWS * HID * 2;        // 16 MB each
    u16* actA   = (u16*)(ws);
    u16* actB   = (u16*)(ws + ACT_BYTES);
    float* Pre  = (float*)(ws + 2 * ACT_BYTES);              // 128*64*128*4 = 4 MB
    char* wbase = ws + 2 * ACT_BYTES + (size_t)NG * 64 * HID * 4;
    u16* Wibf = (u16*)(wbase);
    u16* Wobf = (u16*)(wbase + (size_t)3 * 2 * HID * HID * 2);
    u16* Wpbf = (u16*)(wbase + (size_t)3 * 2 * HID * HID * 2 + (size_t)3 * HID * HID * 2);

    prep_kernel<<<128, 256, 0, stream>>>(Wp, Wi, Wo, Wpbf, Wibf, Wobf);
    proj_kernel<<<NROWS / 64, 256, 0, stream>>>(x, Wpbf, bp, actA);

    u16* cur = actA, *nxt = actB;
    for (int d = 0; d < 3; ++d) {
        chunkh_kernel<<<NG, 512, 0, stream>>>(cur, Pre, log_tau, d);
        fused_kernel<<<NG * 8, 512, 0, stream>>>(cur, Pre,
            Wibf + (size_t)d * 2 * HID * HID, Wobf + (size_t)d * HID * HID,
            bi + d * 2 * HID, bo + d * HID, gm + d * HID, bt + d * HID,
            log_tau, d, nxt);
        u16* t = cur; cur = nxt; nxt = t;
    }
    mean_kernel<<<NG, 512, 0, stream>>>(cur, out);
}